// Round 8
// baseline (266.190 us; speedup 1.0000x reference)
//
#include <hip/hip_runtime.h>
#include <hip/hip_cooperative_groups.h>
#include <math.h>

namespace cg = cooperative_groups;

#define BATCH   256
#define NFEAT   512
#define DMODEL  1024
#define DHALF   512
#define LN_EPS  1e-5f
#define LDSK    68   // transposed LDS tile stride ([kk][m]); 16B-aligned (+4 pad)

typedef float f2 __attribute__((ext_vector_type(2)));
typedef float f4 __attribute__((ext_vector_type(4)));

// ---------------------------------------------------------------------------
// 64x64 GEMM tile as a device function. C = A[M][K] * op(B).
// op(B)=B^T (B:[N][K]) if B_NT else B ([K][N]). LDS transposed As[kk][m],
// Bs[kk][n] -> frag loads are one ds_read_b128 each. SPLIT==1: direct write
// (+bias/+sigmoid); SPLIT>1: partials Cp[z][M][N].
// ---------------------------------------------------------------------------
template <int M, int N, int K, int SPLIT, bool B_NT, bool BIAS, bool SIG>
__device__ __forceinline__ void gemm_tile(
    const float* __restrict__ A, const float* __restrict__ B,
    const float* __restrict__ bias, float* __restrict__ Cp,
    float* __restrict__ As, float* __restrict__ Bs,
    const int bx, const int by, const int z, const int tid) {
  constexpr int KC = K / SPLIT;
  constexpr int NT = KC / 64;
  const int bm = bx * 64, bn = by * 64, kb = z * KC;
  const int tx  = tid & 15;
  const int ty  = tid >> 4;
  const int r16 = tid >> 4;
  const int c4  = tid & 15;
  f4 ar[4], br[4];

  auto load_tile = [&](int t) {
#pragma unroll
    for (int jj = 0; jj < 4; ++jj) {
      const int row = r16 + jj * 16;
      ar[jj] = *(const f4*)(&A[(size_t)(bm + row) * K + kb + t * 64 + c4 * 4]);
      if (B_NT)
        br[jj] = *(const f4*)(&B[(size_t)(bn + row) * K + kb + t * 64 + c4 * 4]);
      else
        br[jj] = *(const f4*)(&B[(size_t)(kb + t * 64 + row) * N + bn + c4 * 4]);
    }
  };
  auto store_tile = [&]() {
#pragma unroll
    for (int jj = 0; jj < 4; ++jj) {
      const int row = r16 + jj * 16;
      As[(c4 * 4 + 0) * LDSK + row] = ar[jj].x;
      As[(c4 * 4 + 1) * LDSK + row] = ar[jj].y;
      As[(c4 * 4 + 2) * LDSK + row] = ar[jj].z;
      As[(c4 * 4 + 3) * LDSK + row] = ar[jj].w;
      if (B_NT) {
        Bs[(c4 * 4 + 0) * LDSK + row] = br[jj].x;
        Bs[(c4 * 4 + 1) * LDSK + row] = br[jj].y;
        Bs[(c4 * 4 + 2) * LDSK + row] = br[jj].z;
        Bs[(c4 * 4 + 3) * LDSK + row] = br[jj].w;
      } else {
        *(f4*)(&Bs[row * LDSK + c4 * 4]) = br[jj];
      }
    }
  };

  f2 acc[4][2];
#pragma unroll
  for (int i = 0; i < 4; ++i) { acc[i][0] = (f2)0.f; acc[i][1] = (f2)0.f; }

  load_tile(0);
  store_tile();
  __syncthreads();

  for (int t = 0; t < NT; ++t) {
    if (t + 1 < NT) load_tile(t + 1);
#pragma unroll 4
    for (int kk = 0; kk < 64; ++kk) {
      const f4 af = *(const f4*)(&As[kk * LDSK + ty * 4]);
      const f4 bf = *(const f4*)(&Bs[kk * LDSK + tx * 4]);
      const f2 b01 = {bf.x, bf.y};
      const f2 b23 = {bf.z, bf.w};
#pragma unroll
      for (int i = 0; i < 4; ++i) {
        const f2 ai = {af[i], af[i]};
        acc[i][0] += ai * b01;  // contract -> v_pk_fma_f32
        acc[i][1] += ai * b23;
      }
    }
    if (t + 1 < NT) {
      __syncthreads();
      store_tile();
      __syncthreads();
    }
  }

  f4 bv = {0.f, 0.f, 0.f, 0.f};
  if (BIAS && SPLIT == 1) bv = *(const f4*)(&bias[bn + tx * 4]);
#pragma unroll
  for (int i = 0; i < 4; ++i) {
    const int m = bm + ty * 4 + i;
    f4 cv = {acc[i][0].x, acc[i][0].y, acc[i][1].x, acc[i][1].y};
    if (SPLIT == 1) {
      if (BIAS) cv += bv;
      if (SIG) {
#pragma unroll
        for (int u = 0; u < 4; ++u) cv[u] = 1.f / (1.f + expf(-cv[u]));
      }
      *(f4*)(&Cp[(size_t)m * N + bn + tx * 4]) = cv;
    } else {
      *(f4*)(&Cp[((size_t)z * M + m) * N + bn + tx * 4]) = cv;
    }
  }
}

// ---------------------------------------------------------------------------
// Coherence for one batch row. 256 threads, 4 i's/thread (i = 4*tid..+3).
// Optionally reduces PARTS phi partials (+bp) first and stores phi.
// cc/ss are 1024-float LDS planes.
// ---------------------------------------------------------------------------
template <int PARTS, bool WRITE_PHI>
__device__ __forceinline__ void coherence_row(
    const float* __restrict__ parts, const float* __restrict__ bp,
    const float* __restrict__ prev_ca, float* __restrict__ phi_out,
    float* __restrict__ ca_out, float* __restrict__ cc, float* __restrict__ ss,
    const int b, const int tid) {
  f4 ph = ((const f4*)(parts + (size_t)b * DMODEL))[tid];
  if (PARTS > 1) {
#pragma unroll
    for (int z = 1; z < PARTS; ++z)
      ph += ((const f4*)(parts + ((size_t)z * BATCH + b) * DMODEL))[tid];
    ph += ((const f4*)bp)[tid];
    if (WRITE_PHI) ((f4*)(phi_out + (size_t)b * DMODEL))[tid] = ph;
  }
  float ci[4], si[4];
#pragma unroll
  for (int u = 0; u < 4; ++u) { si[u] = __sinf(ph[u]); ci[u] = __cosf(ph[u]); }
  *(f4*)(&cc[tid * 4]) = f4{ci[0], ci[1], ci[2], ci[3]};
  *(f4*)(&ss[tid * 4]) = f4{si[0], si[1], si[2], si[3]};
  __syncthreads();

  float accA[4] = {0.f, 0.f, 0.f, 0.f};
  float accB[4] = {0.f, 0.f, 0.f, 0.f};
#pragma unroll 4
  for (int j4 = 0; j4 < DMODEL; j4 += 4) {
    const f4 cy = *(const f4*)(&cc[j4]);  // wave-uniform broadcast
    const f4 sy = *(const f4*)(&ss[j4]);
    const f2 cy01 = {cy.x, cy.y}, cy23 = {cy.z, cy.w};
    const f2 sy01 = {sy.x, sy.y}, sy23 = {sy.z, sy.w};
#pragma unroll
    for (int u = 0; u < 4; ++u) {
      const f2 cu = {ci[u], ci[u]};
      const f2 su = {si[u], si[u]};
      f2 t = su * sy01; t = cu * cy01 + t;
      accA[u] += __builtin_fabsf(t.x);
      accB[u] += __builtin_fabsf(t.y);
      t = su * sy23; t = cu * cy23 + t;
      accA[u] += __builtin_fabsf(t.x);
      accB[u] += __builtin_fabsf(t.y);
    }
  }
  const f4 pc = ((const f4*)(prev_ca + (size_t)b * DMODEL))[tid];
  f4 o;
#pragma unroll
  for (int u = 0; u < 4; ++u)
    o[u] = pc[u] * 0.95f + (accA[u] + accB[u]) * (0.05f / (float)DMODEL);
  ((f4*)(ca_out + (size_t)b * DMODEL))[tid] = o;
}

// ---------------------------------------------------------------------------
// LN epilogue for one batch row. 256 threads, 4 cols/thread. red = 8 LDS f32.
// ---------------------------------------------------------------------------
template <int PCP, int PGP, bool GATE_RAW>
__device__ __forceinline__ void ln_row(
    const float* __restrict__ pC, const float* __restrict__ pG,
    const float* __restrict__ phi, const float* __restrict__ bg,
    const float* __restrict__ gamma, const float* __restrict__ beta,
    float* __restrict__ out, float* __restrict__ red, const int b,
    const int tid) {
  float gs[2];
#pragma unroll
  for (int h = 0; h < 2; ++h) {
    const int gi = tid + h * 256;
    float s = 0.f;
#pragma unroll
    for (int z = 0; z < PGP; ++z)
      s += pG[((size_t)z * BATCH + b) * DHALF + gi];
    if (GATE_RAW) {
      s += bg[gi];
      s = 1.f / (1.f + expf(-s));
    }
    gs[h] = s;
  }
  float hv[4];
  float sum = 0.f, sumsq = 0.f;
#pragma unroll
  for (int u = 0; u < 4; ++u) {
    const int n = tid + u * 256;
    float cpl = 0.f;
#pragma unroll
    for (int z = 0; z < PCP; ++z)
      cpl += pC[((size_t)z * BATCH + b) * DMODEL + n];
    const float v = fmaf(cpl, gs[u & 1], phi[(size_t)b * DMODEL + n]);
    hv[u] = v;
    sum += v;
    sumsq = fmaf(v, v, sumsq);
  }
  const int lane = tid & 63;
  const int wid  = tid >> 6;
#pragma unroll
  for (int off = 32; off > 0; off >>= 1) {
    sum   += __shfl_down(sum, off);
    sumsq += __shfl_down(sumsq, off);
  }
  if (lane == 0) { red[wid] = sum; red[4 + wid] = sumsq; }
  __syncthreads();
  sum   = red[0] + red[1] + red[2] + red[3];
  sumsq = red[4] + red[5] + red[6] + red[7];
  const float mu   = sum * (1.f / DMODEL);
  const float var  = sumsq * (1.f / DMODEL) - mu * mu;
  const float rstd = rsqrtf(var + LN_EPS);
#pragma unroll
  for (int u = 0; u < 4; ++u) {
    const int n = tid + u * 256;
    out[(size_t)b * DMODEL + n] = (hv[u] - mu) * rstd * gamma[n] + beta[n];
  }
}

// ---------------------------------------------------------------------------
// Cooperative mega-kernel: entire pipeline in one dispatch, 512 blocks x 256.
// Phase 1: phi partials (all 512 blocks, split-K 8)
// Phase 2: coherence+phi reduce (blocks 0-255) || W copy (blocks 256-511)
// Phase 3: gate partials split8 (0-255) || coupled partials split4 (256-511)
// Phase 4: LN (0-255)
// ---------------------------------------------------------------------------
__global__ __launch_bounds__(256, 2) void mega_kernel(
    const float* __restrict__ x, const float* __restrict__ prev_ca,
    const float* __restrict__ Wp, const float* __restrict__ bp,
    const float* __restrict__ Wg, const float* __restrict__ bg,
    const float* __restrict__ W, const float* __restrict__ gamma,
    const float* __restrict__ beta, float* __restrict__ out_features,
    float* __restrict__ out_ca, float* __restrict__ out_W,
    float* __restrict__ phi, float* __restrict__ pbuf,
    float* __restrict__ pG, float* __restrict__ pC) {
  __shared__ __align__(16) float lds[2 * 64 * LDSK];  // 34.8 KB
  float* As = lds;
  float* Bs = lds + 64 * LDSK;
  const int gb  = blockIdx.x;
  const int tid = threadIdx.x;
  cg::grid_group grid = cg::this_grid();

  // ---- Phase 1: phi partials: x @ Wp^T -> pbuf[8][256][1024] ----
  {
    const int z = gb >> 6, rem = gb & 63;
    gemm_tile<BATCH, DMODEL, NFEAT, 8, true, false, false>(
        x, Wp, nullptr, pbuf, As, Bs, rem & 3, rem >> 2, z, tid);
  }
  grid.sync();

  // ---- Phase 2: coherence (0-255) || W copy (256-511) ----
  if (gb < 256) {
    coherence_row<8, true>(pbuf, bp, prev_ca, phi, out_ca, As, As + DMODEL,
                           gb, tid);
  } else {
    const int base = (gb - 256) * 1024 + tid;  // 1024 f4 per chunk
    const f4* src = (const f4*)W;
    f4* dst = (f4*)out_W;
#pragma unroll
    for (int k = 0; k < 4; ++k) dst[base + k * 256] = src[base + k * 256];
  }
  grid.sync();

  // ---- Phase 3: gate partials (0-255) || coupled partials (256-511) ----
  if (gb < 256) {
    const int z = gb >> 5, rem = gb & 31;
    gemm_tile<BATCH, DHALF, DMODEL, 8, true, false, false>(
        out_ca, Wg, nullptr, pG, As, Bs, rem & 3, rem >> 2, z, tid);
  } else {
    const int g2 = gb - 256;
    const int z = g2 >> 6, rem = g2 & 63;
    gemm_tile<BATCH, DMODEL, DMODEL, 4, false, false, false>(
        phi, W, nullptr, pC, As, Bs, rem & 3, rem >> 2, z, tid);
  }
  grid.sync();

  // ---- Phase 4: LN (0-255) ----
  if (gb < 256) {
    ln_row<4, 8, true>(pC, pG, phi, bg, gamma, beta, out_features, As, gb,
                       tid);
  }
}

// ---------------------------------------------------------------------------
// Fallback standalone kernels (regular launches; used only if ws too small).
// ---------------------------------------------------------------------------
template <int M, int N, int K, int SPLIT, bool B_NT, bool BIAS, bool SIG>
__global__ __launch_bounds__(256) void gemm64_kernel(
    const float* __restrict__ A, const float* __restrict__ B,
    const float* __restrict__ bias, float* __restrict__ C) {
  __shared__ __align__(16) float lds[2 * 64 * LDSK];
  gemm_tile<M, N, K, SPLIT, B_NT, BIAS, SIG>(A, B, bias, C, lds,
                                             lds + 64 * LDSK, blockIdx.x,
                                             blockIdx.y, blockIdx.z,
                                             threadIdx.x);
}

__global__ __launch_bounds__(256) void coherence_kernel1(
    const float* __restrict__ phi, const float* __restrict__ prev_ca,
    float* __restrict__ ca_out) {
  __shared__ __align__(16) float lds[2 * DMODEL];
  coherence_row<1, false>(phi, nullptr, prev_ca, nullptr, ca_out, lds,
                          lds + DMODEL, blockIdx.x, threadIdx.x);
}

__global__ __launch_bounds__(256) void ln_kernel1(
    const float* __restrict__ pC, const float* __restrict__ pG,
    const float* __restrict__ phi, const float* __restrict__ bg,
    const float* __restrict__ gamma, const float* __restrict__ beta,
    float* __restrict__ out) {
  __shared__ float red[8];
  ln_row<1, 1, false>(pC, pG, phi, bg, gamma, beta, out, red, blockIdx.x,
                      threadIdx.x);
}

// ---------------------------------------------------------------------------
extern "C" void kernel_launch(void* const* d_in, const int* in_sizes, int n_in,
                              void* d_out, int out_size, void* d_ws,
                              size_t ws_size, hipStream_t stream) {
  const float* x       = (const float*)d_in[0];  // [256,512]
  const float* prev_ca = (const float*)d_in[1];  // [256,1024]
  const float* Wp      = (const float*)d_in[2];  // [1024,512]  (NT)
  const float* bp      = (const float*)d_in[3];  // [1024]
  const float* Wg      = (const float*)d_in[4];  // [512,1024]  (NT)
  const float* bg      = (const float*)d_in[5];  // [512]
  const float* W       = (const float*)d_in[6];  // [1024,1024] (NN)
  const float* gamma   = (const float*)d_in[7];  // [1024]
  const float* beta    = (const float*)d_in[8];  // [1024]

  float* out_features = (float*)d_out;                  // [256,1024]
  float* out_ca       = out_features + BATCH * DMODEL;  // [256,1024]
  float* out_W        = out_ca + BATCH * DMODEL;        // [1024,1024]

  float* phi  = (float*)d_ws;                  // 1 MB
  float* pbuf = phi + BATCH * DMODEL;          // 8*[256][1024] = 8 MB
  float* pG   = pbuf + 8 * BATCH * DMODEL;     // 8*[256][512]  = 4 MB
  float* pC   = pG + 8 * BATCH * DHALF;        // 4*[256][1024] = 4 MB

  const size_t need_mega =
      (size_t)(BATCH * DMODEL + 8 * BATCH * DMODEL + 8 * BATCH * DHALF +
               4 * BATCH * DMODEL) * sizeof(float);                // 17 MB
  const size_t need_compact =
      (size_t)(2 * BATCH * DMODEL + BATCH * DHALF) * sizeof(float);  // 2.5 MB

  if (ws_size >= need_mega) {
    void* kargs[] = {(void*)&x,   (void*)&prev_ca, (void*)&Wp,
                     (void*)&bp,  (void*)&Wg,      (void*)&bg,
                     (void*)&W,   (void*)&gamma,   (void*)&beta,
                     (void*)&out_features, (void*)&out_ca, (void*)&out_W,
                     (void*)&phi, (void*)&pbuf,    (void*)&pG,
                     (void*)&pC};
    hipLaunchCooperativeKernel((const void*)mega_kernel, dim3(512), dim3(256),
                               kargs, 0, stream);
  } else {
    // --- compact fallback: regular launches, direct-write GEMMs ---
    float* scratch = (ws_size >= need_compact) ? (float*)d_ws : out_W;
    float* sphi    = scratch;                 // [256,1024]
    float* gate    = sphi + BATCH * DMODEL;   // [256,512]
    float* coupled = gate + BATCH * DHALF;    // [256,1024]
    gemm64_kernel<BATCH, DMODEL, NFEAT, 1, true, true, false>
        <<<dim3(4, 16, 1), 256, 0, stream>>>(x, Wp, bp, sphi);
    coherence_kernel1<<<BATCH, 256, 0, stream>>>(sphi, prev_ca, out_ca);
    gemm64_kernel<BATCH, DHALF, DMODEL, 1, true, true, true>
        <<<dim3(4, 8, 1), 256, 0, stream>>>(out_ca, Wg, bg, gate);
    gemm64_kernel<BATCH, DMODEL, DMODEL, 1, false, false, false>
        <<<dim3(4, 16, 1), 256, 0, stream>>>(sphi, W, nullptr, coupled);
    ln_kernel1<<<BATCH, 256, 0, stream>>>(coupled, gate, sphi, bg, gamma,
                                          beta, out_features);
    hipMemcpyAsync(out_W, W, (size_t)DMODEL * DMODEL * sizeof(float),
                   hipMemcpyDeviceToDevice, stream);
  }
}

// Round 9
// 132.705 us; speedup vs baseline: 2.0059x; 2.0059x over previous
//
#include <hip/hip_runtime.h>
#include <math.h>

#define BATCH   256
#define NFEAT   512
#define DMODEL  1024
#define DHALF   512
#define LN_EPS  1e-5f
#define LDSK    68    // As row stride (floats): 64 + 4, 16B-aligned
#define LDSN    132   // Bs row stride (floats): 128 + 4, 16B-aligned

typedef float f2 __attribute__((ext_vector_type(2)));
typedef float f4 __attribute__((ext_vector_type(4)));

// ---------------------------------------------------------------------------
// GEMM tile 64(M) x 128(N), 256 threads, 4x8 outputs/thread.
//   C = A[M][K] * op(B);  op(B)=B^T (B:[N][K]) if B_NT else B ([K][N]).
// LDS transposed + XOR-swizzled: logical col m of row kk stored at
//   4*((m>>2) ^ ((kk>>2)&15)) + (m&3)   -> staging scatter writes are
// bank-conflict-free AND frag reads stay single b128 (swizzle applied on
// read too; fully unrolled kk loop folds offsets to immediates).
// SPLIT==1: direct write (+bias/+sigmoid). SPLIT>1: partials Cp[z][M][N].
// ---------------------------------------------------------------------------
template <int M, int N, int K, int SPLIT, bool B_NT, bool BIAS, bool SIG>
__device__ __forceinline__ void gemm_tile128(
    const float* __restrict__ A, const float* __restrict__ B,
    const float* __restrict__ bias, float* __restrict__ Cp,
    float* __restrict__ As, float* __restrict__ Bs,
    const int bx, const int by, const int z, const int tid) {
  constexpr int KC = K / SPLIT;
  constexpr int NT = KC / 64;
  const int bm = bx * 64, bn = by * 128, kb = z * KC;
  const int tx  = tid & 15;   // n-group: 8 cols at bn + tx*8
  const int ty  = tid >> 4;   // m-group: 4 rows at bm + ty*4
  const int c4  = tid & 15;   // A/B-NT staging: f4 col
  const int r16 = tid >> 4;   // A/B-NT staging: row base
  const int c8  = tid & 31;   // B-NN staging: f4 col
  const int r8  = tid >> 5;   // B-NN staging: k-row base

  f4 ar[4], br[8];

  auto load_tile = [&](int t) {
#pragma unroll
    for (int jj = 0; jj < 4; ++jj)
      ar[jj] = *(const f4*)(
          &A[(size_t)(bm + r16 + jj * 16) * K + kb + t * 64 + c4 * 4]);
    if (B_NT) {
#pragma unroll
      for (int jj = 0; jj < 8; ++jj)
        br[jj] = *(const f4*)(
            &B[(size_t)(bn + r16 + jj * 16) * K + kb + t * 64 + c4 * 4]);
    } else {
#pragma unroll
      for (int jj = 0; jj < 8; ++jj)
        br[jj] = *(const f4*)(
            &B[(size_t)(kb + t * 64 + r8 + jj * 8) * N + bn + c8 * 4]);
    }
  };
  auto store_tile = [&]() {
    // A: [m][k] -> As[kk][swz(m)] scalar scatter; kk = c4*4+j so the
    // swizzle term (kk>>2)&15 == c4 varies per lane -> conflict-free.
#pragma unroll
    for (int jj = 0; jj < 4; ++jj) {
#pragma unroll
      for (int j = 0; j < 4; ++j) {
        const int kk = c4 * 4 + j;
        const int m  = r16 + jj * 16;
        As[kk * LDSK + ((((m >> 2) ^ c4) << 2) | (m & 3))] = ar[jj][j];
      }
    }
    if (B_NT) {
#pragma unroll
      for (int jj = 0; jj < 8; ++jj) {
#pragma unroll
        for (int j = 0; j < 4; ++j) {
          const int kk = c4 * 4 + j;
          const int n  = r16 + jj * 16;
          Bs[kk * LDSN + ((((n >> 2) ^ c4) << 2) | (n & 3))] = br[jj][j];
        }
      }
    } else {
      // natural b128 writes, swizzle f4-block index
#pragma unroll
      for (int jj = 0; jj < 8; ++jj) {
        const int kk = r8 + jj * 8;
        *(f4*)(&Bs[kk * LDSN + ((c8 ^ ((kk >> 2) & 15)) << 2)]) = br[jj];
      }
    }
  };

  f2 acc[4][4];
#pragma unroll
  for (int i = 0; i < 4; ++i)
#pragma unroll
    for (int p = 0; p < 4; ++p) acc[i][p] = (f2)0.f;

  load_tile(0);
  store_tile();
  __syncthreads();

  for (int t = 0; t < NT; ++t) {
    if (t + 1 < NT) load_tile(t + 1);  // in flight during compute
#pragma unroll
    for (int kk = 0; kk < 64; ++kk) {   // full unroll: offsets -> immediates
      const int gk = (kk >> 2) & 15;
      const f4 af  = *(const f4*)(&As[kk * LDSK + ((ty ^ gk) << 2)]);
      const f4 bf0 = *(const f4*)(&Bs[kk * LDSN + (((2 * tx) ^ gk) << 2)]);
      const f4 bf1 = *(const f4*)(&Bs[kk * LDSN + (((2 * tx + 1) ^ gk) << 2)]);
      const f2 b[4] = {{bf0.x, bf0.y}, {bf0.z, bf0.w},
                       {bf1.x, bf1.y}, {bf1.z, bf1.w}};
#pragma unroll
      for (int i = 0; i < 4; ++i) {
        const f2 ai = {af[i], af[i]};
#pragma unroll
        for (int p = 0; p < 4; ++p) acc[i][p] += ai * b[p];  // v_pk_fma_f32
      }
    }
    if (t + 1 < NT) {
      __syncthreads();
      store_tile();
      __syncthreads();
    }
  }

  f4 bv0 = {0.f, 0.f, 0.f, 0.f}, bv1 = bv0;
  if (BIAS && SPLIT == 1) {
    bv0 = *(const f4*)(&bias[bn + tx * 8]);
    bv1 = *(const f4*)(&bias[bn + tx * 8 + 4]);
  }
#pragma unroll
  for (int i = 0; i < 4; ++i) {
    const int m = bm + ty * 4 + i;
    f4 c0 = {acc[i][0].x, acc[i][0].y, acc[i][1].x, acc[i][1].y};
    f4 c1 = {acc[i][2].x, acc[i][2].y, acc[i][3].x, acc[i][3].y};
    if (SPLIT == 1) {
      if (BIAS) { c0 += bv0; c1 += bv1; }
      if (SIG) {
#pragma unroll
        for (int u = 0; u < 4; ++u) {
          c0[u] = 1.f / (1.f + expf(-c0[u]));
          c1[u] = 1.f / (1.f + expf(-c1[u]));
        }
      }
      *(f4*)(&Cp[(size_t)m * N + bn + tx * 8]) = c0;
      *(f4*)(&Cp[(size_t)m * N + bn + tx * 8 + 4]) = c1;
    } else {
      *(f4*)(&Cp[((size_t)z * M + m) * N + bn + tx * 8]) = c0;
      *(f4*)(&Cp[((size_t)z * M + m) * N + bn + tx * 8 + 4]) = c1;
    }
  }
}

// ---------------------------------------------------------------------------
// Coherence row (256 thr, 4 i/thread). Reduces PARTS phi partials (+bp),
// optionally stores phi, computes ca.
// ---------------------------------------------------------------------------
template <int PARTS, bool WRITE_PHI>
__device__ __forceinline__ void coherence_row(
    const float* __restrict__ parts, const float* __restrict__ bp,
    const float* __restrict__ prev_ca, float* __restrict__ phi_out,
    float* __restrict__ ca_out, float* __restrict__ cc, float* __restrict__ ss,
    const int b, const int tid) {
  f4 ph = ((const f4*)(parts + (size_t)b * DMODEL))[tid];
  if (PARTS > 1) {
#pragma unroll
    for (int z = 1; z < PARTS; ++z)
      ph += ((const f4*)(parts + ((size_t)z * BATCH + b) * DMODEL))[tid];
    ph += ((const f4*)bp)[tid];
    if (WRITE_PHI) ((f4*)(phi_out + (size_t)b * DMODEL))[tid] = ph;
  }
  float ci[4], si[4];
#pragma unroll
  for (int u = 0; u < 4; ++u) { si[u] = __sinf(ph[u]); ci[u] = __cosf(ph[u]); }
  *(f4*)(&cc[tid * 4]) = f4{ci[0], ci[1], ci[2], ci[3]};
  *(f4*)(&ss[tid * 4]) = f4{si[0], si[1], si[2], si[3]};
  __syncthreads();

  float accA[4] = {0.f, 0.f, 0.f, 0.f};
  float accB[4] = {0.f, 0.f, 0.f, 0.f};
#pragma unroll 4
  for (int j4 = 0; j4 < DMODEL; j4 += 4) {
    const f4 cy = *(const f4*)(&cc[j4]);  // wave-uniform broadcast
    const f4 sy = *(const f4*)(&ss[j4]);
    const f2 cy01 = {cy.x, cy.y}, cy23 = {cy.z, cy.w};
    const f2 sy01 = {sy.x, sy.y}, sy23 = {sy.z, sy.w};
#pragma unroll
    for (int u = 0; u < 4; ++u) {
      const f2 cu = {ci[u], ci[u]};
      const f2 su = {si[u], si[u]};
      f2 t = su * sy01; t = cu * cy01 + t;
      accA[u] += __builtin_fabsf(t.x);
      accB[u] += __builtin_fabsf(t.y);
      t = su * sy23; t = cu * cy23 + t;
      accA[u] += __builtin_fabsf(t.x);
      accB[u] += __builtin_fabsf(t.y);
    }
  }
  const f4 pc = ((const f4*)(prev_ca + (size_t)b * DMODEL))[tid];
  f4 o;
#pragma unroll
  for (int u = 0; u < 4; ++u)
    o[u] = pc[u] * 0.95f + (accA[u] + accB[u]) * (0.05f / (float)DMODEL);
  ((f4*)(ca_out + (size_t)b * DMODEL))[tid] = o;
}

// ---------------------------------------------------------------------------
// LN row (256 thr, 4 cols/thread). Reduces PCP coupled / PGP gate partials.
// ---------------------------------------------------------------------------
template <int PCP, int PGP, bool GATE_RAW>
__device__ __forceinline__ void ln_row(
    const float* __restrict__ pC, const float* __restrict__ pG,
    const float* __restrict__ phi, const float* __restrict__ bg,
    const float* __restrict__ gamma, const float* __restrict__ beta,
    float* __restrict__ out, float* __restrict__ red, const int b,
    const int tid) {
  float gs[2];
#pragma unroll
  for (int h = 0; h < 2; ++h) {
    const int gi = tid + h * 256;
    float s = 0.f;
#pragma unroll
    for (int z = 0; z < PGP; ++z)
      s += pG[((size_t)z * BATCH + b) * DHALF + gi];
    if (GATE_RAW) {
      s += bg[gi];
      s = 1.f / (1.f + expf(-s));
    }
    gs[h] = s;
  }
  float hv[4];
  float sum = 0.f, sumsq = 0.f;
#pragma unroll
  for (int u = 0; u < 4; ++u) {
    const int n = tid + u * 256;
    float cpl = 0.f;
#pragma unroll
    for (int z = 0; z < PCP; ++z)
      cpl += pC[((size_t)z * BATCH + b) * DMODEL + n];
    const float v = fmaf(cpl, gs[u & 1], phi[(size_t)b * DMODEL + n]);
    hv[u] = v;
    sum += v;
    sumsq = fmaf(v, v, sumsq);
  }
  const int lane = tid & 63;
  const int wid  = tid >> 6;
#pragma unroll
  for (int off = 32; off > 0; off >>= 1) {
    sum   += __shfl_down(sum, off);
    sumsq += __shfl_down(sumsq, off);
  }
  if (lane == 0) { red[wid] = sum; red[4 + wid] = sumsq; }
  __syncthreads();
  sum   = red[0] + red[1] + red[2] + red[3];
  sumsq = red[4] + red[5] + red[6] + red[7];
  const float mu   = sum * (1.f / DMODEL);
  const float var  = sumsq * (1.f / DMODEL) - mu * mu;
  const float rstd = rsqrtf(var + LN_EPS);
#pragma unroll
  for (int u = 0; u < 4; ++u) {
    const int n = tid + u * 256;
    out[(size_t)b * DMODEL + n] = (hv[u] - mu) * rstd * gamma[n] + beta[n];
  }
}

// ---------------------------------------------------------------------------
// Node 1: phi partials (256 blocks: 4x8 tiles x split8) || W copy (32 blocks)
// ---------------------------------------------------------------------------
__global__ __launch_bounds__(256, 2) void k_phi_wcopy(
    const float* __restrict__ x, const float* __restrict__ Wp,
    float* __restrict__ pbuf, const f4* __restrict__ wsrc,
    f4* __restrict__ wdst) {
  __shared__ __align__(16) float As[64 * LDSK];
  __shared__ __align__(16) float Bs[64 * LDSN];
  const int gb = blockIdx.x, tid = threadIdx.x;
  if (gb < 256) {
    gemm_tile128<BATCH, DMODEL, NFEAT, 8, true, false, false>(
        x, Wp, nullptr, pbuf, As, Bs, gb & 3, (gb >> 2) & 7, gb >> 5, tid);
  } else {
    const int base = (gb - 256) * 8192 + tid;
#pragma unroll
    for (int k = 0; k < 32; ++k) wdst[base + k * 256] = wsrc[base + k * 256];
  }
}

// ---------------------------------------------------------------------------
// Node 2: coherence + phi reduce (256 blocks, one row each)
// ---------------------------------------------------------------------------
__global__ __launch_bounds__(256, 2) void k_coherence(
    const float* __restrict__ pbuf, const float* __restrict__ bp,
    const float* __restrict__ prev_ca, float* __restrict__ phi,
    float* __restrict__ ca_out) {
  __shared__ __align__(16) float lds[2 * DMODEL];
  coherence_row<8, true>(pbuf, bp, prev_ca, phi, ca_out, lds, lds + DMODEL,
                         blockIdx.x, threadIdx.x);
}

// ---------------------------------------------------------------------------
// Node 3: gate partials (blocks 0-255: 4x4 x split16) ||
//         coupled partials (blocks 256-511: 4x8 x split8, NT=2)
// ---------------------------------------------------------------------------
__global__ __launch_bounds__(256, 2) void k_gate_coupled(
    const float* __restrict__ ca, const float* __restrict__ Wg,
    const float* __restrict__ phi, const float* __restrict__ W,
    float* __restrict__ pG, float* __restrict__ pC) {
  __shared__ __align__(16) float As[64 * LDSK];
  __shared__ __align__(16) float Bs[64 * LDSN];
  const int gb = blockIdx.x, tid = threadIdx.x;
  if (gb < 256) {
    gemm_tile128<BATCH, DHALF, DMODEL, 16, true, false, false>(
        ca, Wg, nullptr, pG, As, Bs, gb & 3, (gb >> 2) & 3, gb >> 4, tid);
  } else {
    const int g2 = gb - 256;
    gemm_tile128<BATCH, DMODEL, DMODEL, 8, false, false, false>(
        phi, W, nullptr, pC, As, Bs, g2 & 3, (g2 >> 2) & 7, g2 >> 5, tid);
  }
}

// ---------------------------------------------------------------------------
// Node 4: LN epilogue (256 blocks)
// ---------------------------------------------------------------------------
__global__ __launch_bounds__(256, 2) void k_ln(
    const float* __restrict__ pC, const float* __restrict__ pG,
    const float* __restrict__ phi, const float* __restrict__ bg,
    const float* __restrict__ gamma, const float* __restrict__ beta,
    float* __restrict__ out) {
  __shared__ float red[8];
  ln_row<8, 16, true>(pC, pG, phi, bg, gamma, beta, out, red, blockIdx.x,
                      threadIdx.x);
}

// ---------------------------------------------------------------------------
// Compact-fallback kernels (direct writes, SPLIT=1)
// ---------------------------------------------------------------------------
template <int M, int N, int K, bool B_NT, bool BIAS, bool SIG>
__global__ __launch_bounds__(256, 2) void k_gemm1(
    const float* __restrict__ A, const float* __restrict__ B,
    const float* __restrict__ bias, float* __restrict__ C) {
  __shared__ __align__(16) float As[64 * LDSK];
  __shared__ __align__(16) float Bs[64 * LDSN];
  gemm_tile128<M, N, K, 1, B_NT, BIAS, SIG>(A, B, bias, C, As, Bs,
                                            blockIdx.x, blockIdx.y, 0,
                                            threadIdx.x);
}

__global__ __launch_bounds__(256, 2) void k_coherence1(
    const float* __restrict__ phi, const float* __restrict__ prev_ca,
    float* __restrict__ ca_out) {
  __shared__ __align__(16) float lds[2 * DMODEL];
  coherence_row<1, false>(phi, nullptr, prev_ca, nullptr, ca_out, lds,
                          lds + DMODEL, blockIdx.x, threadIdx.x);
}

__global__ __launch_bounds__(256, 2) void k_ln1(
    const float* __restrict__ pC, const float* __restrict__ pG,
    const float* __restrict__ phi, const float* __restrict__ bg,
    const float* __restrict__ gamma, const float* __restrict__ beta,
    float* __restrict__ out) {
  __shared__ float red[8];
  ln_row<1, 1, false>(pC, pG, phi, bg, gamma, beta, out, red, blockIdx.x,
                      threadIdx.x);
}

// ---------------------------------------------------------------------------
extern "C" void kernel_launch(void* const* d_in, const int* in_sizes, int n_in,
                              void* d_out, int out_size, void* d_ws,
                              size_t ws_size, hipStream_t stream) {
  const float* x       = (const float*)d_in[0];  // [256,512]
  const float* prev_ca = (const float*)d_in[1];  // [256,1024]
  const float* Wp      = (const float*)d_in[2];  // [1024,512]  (NT)
  const float* bp      = (const float*)d_in[3];  // [1024]
  const float* Wg      = (const float*)d_in[4];  // [512,1024]  (NT)
  const float* bg      = (const float*)d_in[5];  // [512]
  const float* W       = (const float*)d_in[6];  // [1024,1024] (NN)
  const float* gamma   = (const float*)d_in[7];  // [1024]
  const float* beta    = (const float*)d_in[8];  // [1024]

  float* out_features = (float*)d_out;                  // [256,1024]
  float* out_ca       = out_features + BATCH * DMODEL;  // [256,1024]
  float* out_W        = out_ca + BATCH * DMODEL;        // [1024,1024]

  float* phi  = (float*)d_ws;               // 1 MB
  float* pbuf = phi + BATCH * DMODEL;       // 8*[256][1024] = 8 MB
  float* pG   = pbuf + 8 * BATCH * DMODEL;  // 16*[256][512] = 8 MB
  float* pC   = pG + 16 * BATCH * DHALF;    // 8*[256][1024] = 8 MB

  const size_t need_main =
      (size_t)(BATCH * DMODEL + 8 * BATCH * DMODEL + 16 * BATCH * DHALF +
               8 * BATCH * DMODEL) * sizeof(float);                 // 25 MB
  const size_t need_compact =
      (size_t)(2 * BATCH * DMODEL + BATCH * DHALF) * sizeof(float);  // 2.5 MB

  if (ws_size >= need_main) {
    // n1: phi partials || W copy   (288 blocks)
    k_phi_wcopy<<<288, 256, 0, stream>>>(x, Wp, pbuf, (const f4*)W,
                                         (f4*)out_W);
    // n2: coherence + phi reduce   (256 blocks)
    k_coherence<<<256, 256, 0, stream>>>(pbuf, bp, prev_ca, phi, out_ca);
    // n3: gate partials || coupled partials   (512 blocks, 2/CU)
    k_gate_coupled<<<512, 256, 0, stream>>>(out_ca, Wg, phi, W, pG, pC);
    // n4: LN  (256 blocks)
    k_ln<<<256, 256, 0, stream>>>(pC, pG, phi, bg, gamma, beta, out_features);
  } else {
    // compact fallback: direct-write GEMMs, 5 nodes + memcpy
    float* scratch = (ws_size >= need_compact) ? (float*)d_ws : out_W;
    float* sphi    = scratch;                 // [256,1024]
    float* gate    = sphi + BATCH * DMODEL;   // [256,512]
    float* coupled = gate + BATCH * DHALF;    // [256,1024]
    k_gemm1<BATCH, DMODEL, NFEAT, true, true, false>
        <<<dim3(4, 8), 256, 0, stream>>>(x, Wp, bp, sphi);
    k_coherence1<<<256, 256, 0, stream>>>(sphi, prev_ca, out_ca);
    k_gemm1<BATCH, DHALF, DMODEL, true, true, true>
        <<<dim3(4, 4), 256, 0, stream>>>(out_ca, Wg, bg, gate);
    k_gemm1<BATCH, DMODEL, DMODEL, false, false, false>
        <<<dim3(4, 8), 256, 0, stream>>>(sphi, W, nullptr, coupled);
    k_ln1<<<256, 256, 0, stream>>>(coupled, gate, sphi, bg, gamma, beta,
                                   out_features);
    hipMemcpyAsync(out_W, W, (size_t)DMODEL * DMODEL * sizeof(float),
                   hipMemcpyDeviceToDevice, stream);
  }
}

// Round 13
// 126.543 us; speedup vs baseline: 2.1035x; 1.0487x over previous
//
#include <hip/hip_runtime.h>
#include <math.h>

#define BATCH   256
#define NFEAT   512
#define DMODEL  1024
#define DHALF   512
#define LN_EPS  1e-5f

typedef float f2 __attribute__((ext_vector_type(2)));
typedef float f4 __attribute__((ext_vector_type(4)));

// ---------------------------------------------------------------------------
// GEMM tile 64x64, 256 threads, 4x4 outputs/thread, XOR-swizzled LDS.
//   C = A[M][K] * op(B);  op(B)=B^T (B:[N][K]) if B_NT else B ([K][N]).
// LDS layout (both A and B): element (kk, col) stored at
//   kk*64 + 4*((col>>2) ^ ((kk>>2)&15)) + (col&3)
// -> staging writes 2-way max, frag reads b128 broadcast 2-way max (free).
// SPLIT==1: direct write (+bias/+sigmoid); SPLIT>1: partials Cp[z][M][N].
// Small LDS (32 KB) + small regs -> 4 blocks/CU co-residency (TLP).
// ---------------------------------------------------------------------------
template <int M, int N, int K, int SPLIT, bool B_NT, bool BIAS, bool SIG>
__device__ __forceinline__ void gemm_tile64(
    const float* __restrict__ A, const float* __restrict__ B,
    const float* __restrict__ bias, float* __restrict__ Cp,
    float* __restrict__ As, float* __restrict__ Bs,
    const int bx, const int by, const int z, const int tid) {
  constexpr int KC = K / SPLIT;
  constexpr int NT = KC / 64;
  const int bm = bx * 64, bn = by * 64, kb = z * KC;
  const int tx  = tid & 15;   // n-group: 4 cols at bn + tx*4
  const int ty  = tid >> 4;   // m-group: 4 rows at bm + ty*4
  const int c4  = tid & 15;   // staging f4 col
  const int r16 = tid >> 4;   // staging row base

  f4 ar[4], br[4];

  auto load_tile = [&](int t) {
#pragma unroll
    for (int jj = 0; jj < 4; ++jj) {
      const int row = r16 + jj * 16;
      ar[jj] = *(const f4*)(&A[(size_t)(bm + row) * K + kb + t * 64 + c4 * 4]);
      if (B_NT)
        br[jj] = *(const f4*)(&B[(size_t)(bn + row) * K + kb + t * 64 + c4 * 4]);
      else
        br[jj] = *(const f4*)(&B[(size_t)(kb + t * 64 + row) * N + bn + c4 * 4]);
    }
  };
  auto store_tile = [&]() {
    // A (and B if NT): [col][k] -> [kk][swz(col)] scalar scatter.
    // kk = c4*4+j: swizzle term == c4 varies per lane -> 2-way max.
#pragma unroll
    for (int jj = 0; jj < 4; ++jj) {
      const int m = r16 + jj * 16;
#pragma unroll
      for (int j = 0; j < 4; ++j) {
        const int kk = c4 * 4 + j;
        As[kk * 64 + ((((m >> 2) ^ c4) << 2) | (m & 3))] = ar[jj][j];
      }
      if (B_NT) {
#pragma unroll
        for (int j = 0; j < 4; ++j) {
          const int kk = c4 * 4 + j;
          Bs[kk * 64 + ((((m >> 2) ^ c4) << 2) | (m & 3))] = br[jj][j];
        }
      } else {
        // natural rows: b128 write, swizzle the f4-block index
        const int kk = m;  // k-row
        *(f4*)(&Bs[kk * 64 + ((c4 ^ ((kk >> 2) & 15)) << 2)]) = br[jj];
      }
    }
  };

  f2 acc[4][2];
#pragma unroll
  for (int i = 0; i < 4; ++i) { acc[i][0] = (f2)0.f; acc[i][1] = (f2)0.f; }

  load_tile(0);
  store_tile();
  __syncthreads();

  for (int t = 0; t < NT; ++t) {
    if (t + 1 < NT) load_tile(t + 1);  // reg-staged prefetch
#pragma unroll
    for (int kk = 0; kk < 64; ++kk) {  // full unroll: offsets -> immediates
      const int gk = (kk >> 2) & 15;
      const f4 af = *(const f4*)(&As[kk * 64 + ((ty ^ gk) << 2)]);
      const f4 bf = *(const f4*)(&Bs[kk * 64 + ((tx ^ gk) << 2)]);
      const f2 b01 = {bf.x, bf.y};
      const f2 b23 = {bf.z, bf.w};
#pragma unroll
      for (int i = 0; i < 4; ++i) {
        const f2 ai = {af[i], af[i]};
        acc[i][0] += ai * b01;  // v_pk_fma_f32
        acc[i][1] += ai * b23;
      }
    }
    if (t + 1 < NT) {
      __syncthreads();
      store_tile();
      __syncthreads();
    }
  }

  f4 bv = {0.f, 0.f, 0.f, 0.f};
  if (BIAS && SPLIT == 1) bv = *(const f4*)(&bias[bn + tx * 4]);
#pragma unroll
  for (int i = 0; i < 4; ++i) {
    const int m = bm + ty * 4 + i;
    f4 cv = {acc[i][0].x, acc[i][0].y, acc[i][1].x, acc[i][1].y};
    if (SPLIT == 1) {
      if (BIAS) cv += bv;
      if (SIG) {
#pragma unroll
        for (int u = 0; u < 4; ++u) cv[u] = 1.f / (1.f + expf(-cv[u]));
      }
      *(f4*)(&Cp[(size_t)m * N + bn + tx * 4]) = cv;
    } else {
      *(f4*)(&Cp[((size_t)z * M + m) * N + bn + tx * 4]) = cv;
    }
  }
}

// ---------------------------------------------------------------------------
// Coherence row (256 thr, 4 i/thread). Reduces PARTS phi partials (+bp),
// optionally stores phi, computes ca.
// ---------------------------------------------------------------------------
template <int PARTS, bool WRITE_PHI>
__device__ __forceinline__ void coherence_row(
    const float* __restrict__ parts, const float* __restrict__ bp,
    const float* __restrict__ prev_ca, float* __restrict__ phi_out,
    float* __restrict__ ca_out, float* __restrict__ cc, float* __restrict__ ss,
    const int b, const int tid) {
  f4 ph = ((const f4*)(parts + (size_t)b * DMODEL))[tid];
  if (PARTS > 1) {
#pragma unroll
    for (int z = 1; z < PARTS; ++z)
      ph += ((const f4*)(parts + ((size_t)z * BATCH + b) * DMODEL))[tid];
    ph += ((const f4*)bp)[tid];
    if (WRITE_PHI) ((f4*)(phi_out + (size_t)b * DMODEL))[tid] = ph;
  }
  float ci[4], si[4];
#pragma unroll
  for (int u = 0; u < 4; ++u) { si[u] = __sinf(ph[u]); ci[u] = __cosf(ph[u]); }
  *(f4*)(&cc[tid * 4]) = f4{ci[0], ci[1], ci[2], ci[3]};
  *(f4*)(&ss[tid * 4]) = f4{si[0], si[1], si[2], si[3]};
  __syncthreads();

  float accA[4] = {0.f, 0.f, 0.f, 0.f};
  float accB[4] = {0.f, 0.f, 0.f, 0.f};
#pragma unroll 4
  for (int j4 = 0; j4 < DMODEL; j4 += 4) {
    const f4 cy = *(const f4*)(&cc[j4]);  // wave-uniform broadcast
    const f4 sy = *(const f4*)(&ss[j4]);
    const f2 cy01 = {cy.x, cy.y}, cy23 = {cy.z, cy.w};
    const f2 sy01 = {sy.x, sy.y}, sy23 = {sy.z, sy.w};
#pragma unroll
    for (int u = 0; u < 4; ++u) {
      const f2 cu = {ci[u], ci[u]};
      const f2 su = {si[u], si[u]};
      f2 t = su * sy01; t = cu * cy01 + t;
      accA[u] += __builtin_fabsf(t.x);
      accB[u] += __builtin_fabsf(t.y);
      t = su * sy23; t = cu * cy23 + t;
      accA[u] += __builtin_fabsf(t.x);
      accB[u] += __builtin_fabsf(t.y);
    }
  }
  const f4 pc = ((const f4*)(prev_ca + (size_t)b * DMODEL))[tid];
  f4 o;
#pragma unroll
  for (int u = 0; u < 4; ++u)
    o[u] = pc[u] * 0.95f + (accA[u] + accB[u]) * (0.05f / (float)DMODEL);
  ((f4*)(ca_out + (size_t)b * DMODEL))[tid] = o;
}

// ---------------------------------------------------------------------------
// LN row, fully f4-vectorized. Thread owns cols 4*tid..+3; gate f4 index is
// (tid & 127) since gate tiles [0,512) twice. PCP/PGP independent partial
// loads give deep MLP.
// ---------------------------------------------------------------------------
template <int PCP, int PGP, bool GATE_RAW>
__device__ __forceinline__ void ln_row(
    const float* __restrict__ pC, const float* __restrict__ pG,
    const float* __restrict__ phi, const float* __restrict__ bg,
    const float* __restrict__ gamma, const float* __restrict__ beta,
    float* __restrict__ out, float* __restrict__ red, const int b,
    const int tid) {
  const int gi = tid & 127;  // f4 index into [DHALF]
  f4 g = {0.f, 0.f, 0.f, 0.f};
#pragma unroll
  for (int z = 0; z < PGP; ++z)
    g += ((const f4*)(pG + ((size_t)z * BATCH + b) * DHALF))[gi];
  if (GATE_RAW) {
    g += ((const f4*)bg)[gi];
#pragma unroll
    for (int u = 0; u < 4; ++u) g[u] = 1.f / (1.f + expf(-g[u]));
  }
  f4 cpl = {0.f, 0.f, 0.f, 0.f};
#pragma unroll
  for (int z = 0; z < PCP; ++z)
    cpl += ((const f4*)(pC + ((size_t)z * BATCH + b) * DMODEL))[tid];
  const f4 phv = ((const f4*)(phi + (size_t)b * DMODEL))[tid];
  const f4 h = cpl * g + phv;

  float sum   = h.x + h.y + h.z + h.w;
  float sumsq = h.x * h.x + h.y * h.y + h.z * h.z + h.w * h.w;
  const int lane = tid & 63;
  const int wid  = tid >> 6;
#pragma unroll
  for (int off = 32; off > 0; off >>= 1) {
    sum   += __shfl_down(sum, off);
    sumsq += __shfl_down(sumsq, off);
  }
  if (lane == 0) { red[wid] = sum; red[4 + wid] = sumsq; }
  __syncthreads();
  sum   = red[0] + red[1] + red[2] + red[3];
  sumsq = red[4] + red[5] + red[6] + red[7];
  const float mu   = sum * (1.f / DMODEL);
  const float var  = sumsq * (1.f / DMODEL) - mu * mu;
  const float rstd = rsqrtf(var + LN_EPS);
  const f4 gm = ((const f4*)gamma)[tid];
  const f4 bt = ((const f4*)beta)[tid];
  f4 o;
#pragma unroll
  for (int u = 0; u < 4; ++u) o[u] = (h[u] - mu) * rstd * gm[u] + bt[u];
  ((f4*)(out + (size_t)b * DMODEL))[tid] = o;
}

// ---------------------------------------------------------------------------
// Node 1: phi partials (512 blocks: 4x16 tiles x split8) || W copy (32)
// ---------------------------------------------------------------------------
__global__ __launch_bounds__(256, 4) void k_phi_wcopy(
    const float* __restrict__ x, const float* __restrict__ Wp,
    float* __restrict__ pbuf, const f4* __restrict__ wsrc,
    f4* __restrict__ wdst) {
  __shared__ __align__(16) float As[64 * 64];
  __shared__ __align__(16) float Bs[64 * 64];
  const int gb = blockIdx.x, tid = threadIdx.x;
  if (gb < 512) {
    gemm_tile64<BATCH, DMODEL, NFEAT, 8, true, false, false>(
        x, Wp, nullptr, pbuf, As, Bs, gb & 3, (gb >> 2) & 15, gb >> 6, tid);
  } else {
    const int base = (gb - 512) * 8192 + tid;
#pragma unroll
    for (int k = 0; k < 32; ++k) wdst[base + k * 256] = wsrc[base + k * 256];
  }
}

// ---------------------------------------------------------------------------
// Node 2: coherence + phi reduce (256 blocks)
// ---------------------------------------------------------------------------
__global__ __launch_bounds__(256, 2) void k_coherence(
    const float* __restrict__ pbuf, const float* __restrict__ bp,
    const float* __restrict__ prev_ca, float* __restrict__ phi,
    float* __restrict__ ca_out) {
  __shared__ __align__(16) float lds[2 * DMODEL];
  coherence_row<8, true>(pbuf, bp, prev_ca, phi, ca_out, lds, lds + DMODEL,
                         blockIdx.x, threadIdx.x);
}

// ---------------------------------------------------------------------------
// Node 3: gate partials (blocks 0-511: 4x8 x split16) ||
//         coupled partials (blocks 512-1535: 4x16 x split16)
// ---------------------------------------------------------------------------
__global__ __launch_bounds__(256, 4) void k_gate_coupled(
    const float* __restrict__ ca, const float* __restrict__ Wg,
    const float* __restrict__ phi, const float* __restrict__ W,
    float* __restrict__ pG, float* __restrict__ pC) {
  __shared__ __align__(16) float As[64 * 64];
  __shared__ __align__(16) float Bs[64 * 64];
  const int gb = blockIdx.x, tid = threadIdx.x;
  if (gb < 512) {
    gemm_tile64<BATCH, DHALF, DMODEL, 16, true, false, false>(
        ca, Wg, nullptr, pG, As, Bs, gb & 3, (gb >> 2) & 7, gb >> 5, tid);
  } else {
    const int g2 = gb - 512;
    gemm_tile64<BATCH, DMODEL, DMODEL, 16, false, false, false>(
        phi, W, nullptr, pC, As, Bs, g2 & 3, (g2 >> 2) & 15, g2 >> 6, tid);
  }
}

// ---------------------------------------------------------------------------
// Node 4: LN epilogue (256 blocks)
// ---------------------------------------------------------------------------
__global__ __launch_bounds__(256, 4) void k_ln(
    const float* __restrict__ pC, const float* __restrict__ pG,
    const float* __restrict__ phi, const float* __restrict__ bg,
    const float* __restrict__ gamma, const float* __restrict__ beta,
    float* __restrict__ out) {
  __shared__ float red[8];
  ln_row<16, 16, true>(pC, pG, phi, bg, gamma, beta, out, red, blockIdx.x,
                       threadIdx.x);
}

// ---------------------------------------------------------------------------
// Compact-fallback kernels (direct writes, SPLIT=1)
// ---------------------------------------------------------------------------
template <int M, int N, int K, bool B_NT, bool BIAS, bool SIG>
__global__ __launch_bounds__(256, 4) void k_gemm1(
    const float* __restrict__ A, const float* __restrict__ B,
    const float* __restrict__ bias, float* __restrict__ C) {
  __shared__ __align__(16) float As[64 * 64];
  __shared__ __align__(16) float Bs[64 * 64];
  gemm_tile64<M, N, K, 1, B_NT, BIAS, SIG>(A, B, bias, C, As, Bs, blockIdx.x,
                                           blockIdx.y, 0, threadIdx.x);
}

__global__ __launch_bounds__(256, 2) void k_coherence1(
    const float* __restrict__ phi, const float* __restrict__ prev_ca,
    float* __restrict__ ca_out) {
  __shared__ __align__(16) float lds[2 * DMODEL];
  coherence_row<1, false>(phi, nullptr, prev_ca, nullptr, ca_out, lds,
                          lds + DMODEL, blockIdx.x, threadIdx.x);
}

__global__ __launch_bounds__(256, 4) void k_ln1(
    const float* __restrict__ pC, const float* __restrict__ pG,
    const float* __restrict__ phi, const float* __restrict__ bg,
    const float* __restrict__ gamma, const float* __restrict__ beta,
    float* __restrict__ out) {
  __shared__ float red[8];
  ln_row<1, 1, false>(pC, pG, phi, bg, gamma, beta, out, red, blockIdx.x,
                      threadIdx.x);
}

// ---------------------------------------------------------------------------
extern "C" void kernel_launch(void* const* d_in, const int* in_sizes, int n_in,
                              void* d_out, int out_size, void* d_ws,
                              size_t ws_size, hipStream_t stream) {
  const float* x       = (const float*)d_in[0];  // [256,512]
  const float* prev_ca = (const float*)d_in[1];  // [256,1024]
  const float* Wp      = (const float*)d_in[2];  // [1024,512]  (NT)
  const float* bp      = (const float*)d_in[3];  // [1024]
  const float* Wg      = (const float*)d_in[4];  // [512,1024]  (NT)
  const float* bg      = (const float*)d_in[5];  // [512]
  const float* W       = (const float*)d_in[6];  // [1024,1024] (NN)
  const float* gamma   = (const float*)d_in[7];  // [1024]
  const float* beta    = (const float*)d_in[8];  // [1024]

  float* out_features = (float*)d_out;                  // [256,1024]
  float* out_ca       = out_features + BATCH * DMODEL;  // [256,1024]
  float* out_W        = out_ca + BATCH * DMODEL;        // [1024,1024]

  float* phi  = (float*)d_ws;               // 1 MB
  float* pbuf = phi + BATCH * DMODEL;       // 8*[256][1024]  = 8 MB
  float* pG   = pbuf + 8 * BATCH * DMODEL;  // 16*[256][512]  = 8 MB
  float* pC   = pG + 16 * BATCH * DHALF;    // 16*[256][1024] = 16 MB

  const size_t need_main =
      (size_t)(BATCH * DMODEL + 8 * BATCH * DMODEL + 16 * BATCH * DHALF +
               16 * BATCH * DMODEL) * sizeof(float);                // 33 MB
  const size_t need_compact =
      (size_t)(2 * BATCH * DMODEL + BATCH * DHALF) * sizeof(float);  // 2.5 MB

  if (ws_size >= need_main) {
    // n1: phi partials || W copy   (544 blocks)
    k_phi_wcopy<<<544, 256, 0, stream>>>(x, Wp, pbuf, (const f4*)W,
                                         (f4*)out_W);
    // n2: coherence + phi reduce   (256 blocks)
    k_coherence<<<256, 256, 0, stream>>>(pbuf, bp, prev_ca, phi, out_ca);
    // n3: gate partials || coupled partials   (1536 blocks, ~6/CU queued)
    k_gate_coupled<<<1536, 256, 0, stream>>>(out_ca, Wg, phi, W, pG, pC);
    // n4: LN  (256 blocks)
    k_ln<<<256, 256, 0, stream>>>(pC, pG, phi, bg, gamma, beta, out_features);
  } else {
    // compact fallback: direct-write GEMMs, 5 nodes + memcpy
    float* scratch = (ws_size >= need_compact) ? (float*)d_ws : out_W;
    float* sphi    = scratch;                 // [256,1024]
    float* gate    = sphi + BATCH * DMODEL;   // [256,512]
    float* coupled = gate + BATCH * DHALF;    // [256,1024]
    k_gemm1<BATCH, DMODEL, NFEAT, true, true, false>
        <<<dim3(4, 16), 256, 0, stream>>>(x, Wp, bp, sphi);
    k_coherence1<<<256, 256, 0, stream>>>(sphi, prev_ca, out_ca);
    k_gemm1<BATCH, DHALF, DMODEL, true, true, true>
        <<<dim3(4, 8), 256, 0, stream>>>(out_ca, Wg, bg, gate);
    k_gemm1<BATCH, DMODEL, DMODEL, false, false, false>
        <<<dim3(4, 16), 256, 0, stream>>>(sphi, W, nullptr, coupled);
    k_ln1<<<256, 256, 0, stream>>>(coupled, gate, sphi, bg, gamma, beta,
                                   out_features);
    hipMemcpyAsync(out_W, W, (size_t)DMODEL * DMODEL * sizeof(float),
                   hipMemcpyDeviceToDevice, stream);
  }
}